// Round 1
// baseline (153.653 us; speedup 1.0000x reference)
//
#include <hip/hip_runtime.h>

// Scaled dot-product attention, B=16 L=2048 D=128, fp32 in/out.
// Strategy: prep kernels convert to bf16 (Q pre-scaled, masked rows zeroed,
// V transposed) into d_ws; main kernel is a flash-attention with
// mfma_f32_32x32x16_bf16, swapped QK^T (lane-local P rows), wave-group
// online max (scalar rescale), cvt_pk+permlane32_swap P->A-frag, XOR-swizzled
// LDS tiles, double-buffered staging, XCD-aware block swizzle.

#define NB 16
#define LL 2048
#define DD 128

typedef __attribute__((ext_vector_type(8))) short short8;
typedef __attribute__((ext_vector_type(16))) float f32x16;

__device__ __forceinline__ float wexp2(float x) {
  float r; asm("v_exp_f32 %0, %1" : "=v"(r) : "v"(x)); return r;
}
__device__ __forceinline__ unsigned cvtpk(float lo, float hi) {
  unsigned r; asm("v_cvt_pk_bf16_f32 %0, %1, %2" : "=v"(r) : "v"(lo), "v"(hi)); return r;
}

// ---------------- prep: Q*scale -> bf16, masked rows -> 0 ----------------
__global__ void prep_qmask(const float* __restrict__ Q, const float* __restrict__ scale,
                           const int* __restrict__ mask, short* __restrict__ Qb) {
  int g = blockIdx.x * 256 + threadIdx.x;       // 524288 groups of 8 elems
  float sc = scale[0];
  float msc = (mask[g >> 4] == -1) ? 0.f : sc;  // 8 elems per g, 16 g per row
  const float4* qp = (const float4*)Q + (size_t)g * 2;
  float4 a = qp[0], c = qp[1];
  uint4 o = make_uint4(cvtpk(a.x * msc, a.y * msc), cvtpk(a.z * msc, a.w * msc),
                       cvtpk(c.x * msc, c.y * msc), cvtpk(c.z * msc, c.w * msc));
  ((uint4*)Qb)[g] = o;
}

// ---------------- prep: plain fp32 -> bf16 (K) ----------------
__global__ void prep_cvt(const float* __restrict__ X, short* __restrict__ Xb) {
  int g = blockIdx.x * 256 + threadIdx.x;
  const float4* xp = (const float4*)X + (size_t)g * 2;
  float4 a = xp[0], c = xp[1];
  uint4 o = make_uint4(cvtpk(a.x, a.y), cvtpk(a.z, a.w),
                       cvtpk(c.x, c.y), cvtpk(c.z, c.w));
  ((uint4*)Xb)[g] = o;
}

// ---------------- prep: V -> bf16 transposed Vt[b][d][kv] ----------------
// One block per 64(kv) x 128(d) tile; LDS pitch 130 to break bank conflicts.
__global__ void prep_vt(const float* __restrict__ V, short* __restrict__ Vt) {
  __shared__ short lds[64 * 130];
  int b = blockIdx.x >> 5;
  int t0 = (blockIdx.x & 31) * 64;
  int t = threadIdx.x;
  #pragma unroll
  for (int i = 0; i < 8; ++i) {
    int c = t + i * 256;                  // 2048 float4 chunks
    int kv = c >> 5, ds = (c & 31) * 4;
    float4 v = *(const float4*)(V + ((size_t)(b * LL + t0 + kv) * DD + ds));
    unsigned* dst = (unsigned*)(&lds[kv * 130 + ds]);
    dst[0] = cvtpk(v.x, v.y);
    dst[1] = cvtpk(v.z, v.w);
  }
  __syncthreads();
  int d = t >> 1, hf = t & 1;             // 2 threads per d-row
  unsigned dw[16];
  #pragma unroll
  for (int i = 0; i < 16; ++i) {
    int kv = hf * 32 + i * 2;
    unsigned lo16 = (unsigned short)lds[kv * 130 + d];
    unsigned hi16 = (unsigned short)lds[(kv + 1) * 130 + d];
    dw[i] = lo16 | (hi16 << 16);
  }
  short* orow = Vt + (size_t)(b * DD + d) * LL + t0 + hf * 32;
  #pragma unroll
  for (int i = 0; i < 4; ++i)
    ((uint4*)orow)[i] = make_uint4(dw[4 * i], dw[4 * i + 1], dw[4 * i + 2], dw[4 * i + 3]);
}

// ---------------- main flash attention ----------------
// grid 256 (b, qblock of 128), 256 threads = 4 waves x 32 q-rows.
// LDS: K dbuf 2x16KB @0, V dbuf 2x16KB @32768 (exactly 64KB).
__global__ __launch_bounds__(256, 1) void attn_main(
    const short* __restrict__ Qb, const short* __restrict__ Kb,
    const short* __restrict__ Vt, float* __restrict__ Out) {
  __shared__ __align__(16) char smem[65536];
  const int tid = threadIdx.x;
  const int w = tid >> 6, l = tid & 63, lo = l & 31, hi = l >> 5;

  // bijective XCD swizzle: each batch's 16 blocks -> one XCD (256 = 8*32)
  int lg = (blockIdx.x & 7) * 32 + (blockIdx.x >> 3);
  int b = lg >> 4;
  int q0 = (lg & 15) * 128 + w * 32;

  // Q fragments in registers: lane l holds Q[q0+lo][dc*16 + hi*8 .. +8]
  short8 qf[8];
  const short* qp = Qb + (size_t)(b * LL + q0 + lo) * DD;
  #pragma unroll
  for (int dc = 0; dc < 8; ++dc)
    qf[dc] = *(const short8*)(qp + dc * 16 + hi * 8);

  const short* kg = Kb + (size_t)b * (LL * DD);
  const short* vg = Vt + (size_t)b * (LL * DD);

  int4 kreg[4], vreg[4];

#define STAGE_LOAD(kv0_) { \
    const short* kgp = kg + (size_t)(kv0_) * DD; \
    const short* vgp = vg + (kv0_); \
    _Pragma("unroll") \
    for (int i = 0; i < 4; ++i) { \
      int ck = tid + i * 256; \
      kreg[i] = *(const int4*)(kgp + (ck >> 4) * DD + ((ck & 15) << 3)); \
      vreg[i] = *(const int4*)(vgp + (size_t)(ck >> 3) * LL + ((ck & 7) << 3)); \
    } }

#define STAGE_WRITE(kb_, vb_) { \
    _Pragma("unroll") \
    for (int i = 0; i < 4; ++i) { \
      int ck = tid + i * 256; \
      int kr = ck >> 4, kc = (ck & 15) << 4; \
      *(int4*)(smem + (kb_) + kr * 256 + (kc ^ ((kr & 7) << 4))) = kreg[i]; \
      int vr = ck >> 3, vc = (ck & 7) << 4; \
      *(int4*)(smem + (vb_) + vr * 128 + (vc ^ ((vr & 7) << 4))) = vreg[i]; \
    } }

  STAGE_LOAD(0)
  STAGE_WRITE(0, 32768)
  __syncthreads();

  f32x16 oacc[4];
  #pragma unroll
  for (int dt = 0; dt < 4; ++dt)
    #pragma unroll
    for (int r = 0; r < 16; ++r) oacc[dt][r] = 0.f;
  float m = -INFINITY, lsum = 0.f;

  const int swzk = (lo & 7) << 4;

  #pragma unroll 1
  for (int tt = 0; tt < 32; ++tt) {
    int cur = tt & 1;
    if (tt < 31) STAGE_LOAD((tt + 1) * 64)     // issue early (T14)
    const char* kb = smem + cur * 16384;
    const char* vb = smem + 32768 + cur * 16384;

    #pragma unroll
    for (int s = 0; s < 2; ++s) {
      // --- QK^T swapped: S^T = mfma(Kfrag, Qfrag); lane holds S[q=lo][k=crow(r,hi)]
      f32x16 acc;
      #pragma unroll
      for (int r = 0; r < 16; ++r) acc[r] = 0.f;
      const char* krow = kb + (s * 32 + lo) * 256;
      #pragma unroll
      for (int dc = 0; dc < 8; ++dc) {
        short8 kf = *(const short8*)(krow + ((dc * 32 + hi * 16) ^ swzk));
        acc = __builtin_amdgcn_mfma_f32_32x32x16_bf16(kf, qf[dc], acc, 0, 0, 0);
      }
      // --- wave-group online max (scalar rescale factor)
      float tmax = acc[0];
      #pragma unroll
      for (int r = 1; r < 16; ++r) tmax = fmaxf(tmax, acc[r]);
      #pragma unroll
      for (int off = 1; off < 64; off <<= 1) tmax = fmaxf(tmax, __shfl_xor(tmax, off));
      if (tmax > m) {
        float al = wexp2((m - tmax) * 1.44269504f);
        m = tmax;
        lsum *= al;
        #pragma unroll
        for (int dt = 0; dt < 4; ++dt)
          #pragma unroll
          for (int r = 0; r < 16; ++r) oacc[dt][r] *= al;
      }
      float ps = 0.f;
      #pragma unroll
      for (int r = 0; r < 16; ++r) {
        float p = wexp2((acc[r] - m) * 1.44269504f);
        acc[r] = p; ps += p;
      }
      lsum += ps;
      // --- P -> bf16 A-frags: cvt_pk + permlane32_swap (T12)
      short8 pa[2];
      #pragma unroll
      for (int ks = 0; ks < 2; ++ks) {
        unsigned a0 = cvtpk(acc[ks * 8 + 0], acc[ks * 8 + 1]);
        unsigned b0 = cvtpk(acc[ks * 8 + 4], acc[ks * 8 + 5]);
        unsigned c0 = cvtpk(acc[ks * 8 + 2], acc[ks * 8 + 3]);
        unsigned d0 = cvtpk(acc[ks * 8 + 6], acc[ks * 8 + 7]);
        asm volatile("v_permlane32_swap_b32 %0, %1" : "+v"(a0), "+v"(b0));
        asm volatile("v_permlane32_swap_b32 %0, %1" : "+v"(c0), "+v"(d0));
        union { unsigned u[4]; short8 s; } pu;
        pu.u[0] = a0; pu.u[1] = c0; pu.u[2] = b0; pu.u[3] = d0;
        pa[ks] = pu.s;
      }
      // --- PV: O[q][d] += P*V ; B-frag from transposed V tile
      #pragma unroll
      for (int dt = 0; dt < 4; ++dt) {
        const char* vrow = vb + (dt * 32 + lo) * 128;
        #pragma unroll
        for (int ks = 0; ks < 2; ++ks) {
          short8 vf = *(const short8*)(vrow + ((s * 64 + ks * 32 + hi * 16) ^ swzk));
          oacc[dt] = __builtin_amdgcn_mfma_f32_32x32x16_bf16(pa[ks], vf, oacc[dt], 0, 0, 0);
        }
      }
    }
    __syncthreads();
    if (tt < 31) STAGE_WRITE((cur ^ 1) * 16384, 32768 + (cur ^ 1) * 16384)
    __syncthreads();
  }

  // ---- finalize: combine lsum halves, transpose 1/lsum via LDS (K buf dead)
  float lt = lsum + __shfl_xor(lsum, 32);
  float rd = 1.0f / lt;
  float* lbuf = (float*)smem;
  if (l < 32) lbuf[w * 32 + l] = rd;
  #pragma unroll
  for (int r = 0; r < 16; ++r) {
    int cr = (r & 3) + 8 * (r >> 2) + 4 * hi;
    float rr = lbuf[w * 32 + cr];
    float* op = Out + (size_t)(b * LL + q0 + cr) * DD + lo;
    #pragma unroll
    for (int dt = 0; dt < 4; ++dt)
      op[dt * 32] = oacc[dt][r] * rr;
  }
#undef STAGE_LOAD
#undef STAGE_WRITE
}

extern "C" void kernel_launch(void* const* d_in, const int* in_sizes, int n_in,
                              void* d_out, int out_size, void* d_ws, size_t ws_size,
                              hipStream_t stream) {
  const float* Q = (const float*)d_in[0];
  const float* K = (const float*)d_in[1];
  const float* V = (const float*)d_in[2];
  const float* scale = (const float*)d_in[3];
  const int* mask = (const int*)d_in[4];
  float* out = (float*)d_out;

  const size_t tensor_elems = (size_t)NB * LL * DD;      // 4,194,304
  const size_t need = 3 * tensor_elems * sizeof(short);  // 25,165,824 B
  if (ws_size < need) return;  // fail cleanly rather than corrupt memory

  short* Qb = (short*)d_ws;
  short* Kb = Qb + tensor_elems;
  short* Vtp = Kb + tensor_elems;

  hipLaunchKernelGGL(prep_qmask, dim3(2048), dim3(256), 0, stream, Q, scale, mask, Qb);
  hipLaunchKernelGGL(prep_cvt, dim3(2048), dim3(256), 0, stream, K, Kb);
  hipLaunchKernelGGL(prep_vt, dim3(512), dim3(256), 0, stream, V, Vtp);
  hipLaunchKernelGGL(attn_main, dim3(256), dim3(256), 0, stream, Qb, Kb, Vtp, out);
}

// Round 2
// 71.207 us; speedup vs baseline: 2.1578x; 2.1578x over previous
//
#include <hip/hip_runtime.h>

// Scaled dot-product attention, B=16 L=2048 D=128, fp32 in/out.
// R2: 8 waves/block (4 q-subtiles x 2 kv-halves -> 2 waves/SIMD),
// global_load_lds staging with pre-swizzled source (1 barrier/tile),
// 16-slot K swizzle, defer-max (THR=8), end-of-block pair merge via LDS.

#define NB 16
#define LL 2048
#define DD 128
#define LOG2E 1.44269504f

typedef __attribute__((ext_vector_type(8))) short short8;
typedef __attribute__((ext_vector_type(16))) float f32x16;

__device__ __forceinline__ float wexp2(float x) {
  float r; asm("v_exp_f32 %0, %1" : "=v"(r) : "v"(x)); return r;
}
__device__ __forceinline__ unsigned cvtpk(float lo, float hi) {
  unsigned r; asm("v_cvt_pk_bf16_f32 %0, %1, %2" : "=v"(r) : "v"(lo), "v"(hi)); return r;
}
__device__ __forceinline__ void gll16(const void* g, const void* l) {
  __builtin_amdgcn_global_load_lds(
      (const __attribute__((address_space(1))) unsigned*)g,
      (__attribute__((address_space(3))) unsigned*)l, 16, 0, 0);
}

// ---------------- prep: Q*scale (masked rows -> 0) and K -> bf16 ----------------
__global__ void prep_qk(const float* __restrict__ Q, const float* __restrict__ K,
                        const float* __restrict__ scale, const int* __restrict__ mask,
                        short* __restrict__ Qb, short* __restrict__ Kb) {
  int bid = blockIdx.x;
  int g = ((bid & 2047) << 8) + threadIdx.x;    // 8 elems per g
  if (bid < 2048) {
    float sc = scale[0];
    float msc = (mask[g >> 4] == -1) ? 0.f : sc;
    const float4* qp = (const float4*)Q + (size_t)g * 2;
    float4 a = qp[0], c = qp[1];
    ((uint4*)Qb)[g] = make_uint4(cvtpk(a.x * msc, a.y * msc), cvtpk(a.z * msc, a.w * msc),
                                 cvtpk(c.x * msc, c.y * msc), cvtpk(c.z * msc, c.w * msc));
  } else {
    const float4* kp = (const float4*)K + (size_t)g * 2;
    float4 a = kp[0], c = kp[1];
    ((uint4*)Kb)[g] = make_uint4(cvtpk(a.x, a.y), cvtpk(a.z, a.w),
                                 cvtpk(c.x, c.y), cvtpk(c.z, c.w));
  }
}

// ---------------- prep: V -> bf16 transposed Vt[b][d][kv] ----------------
__global__ void prep_vt(const float* __restrict__ V, short* __restrict__ Vt) {
  __shared__ short lds[64 * 130];
  int b = blockIdx.x >> 5;
  int t0 = (blockIdx.x & 31) * 64;
  int t = threadIdx.x;
  #pragma unroll
  for (int i = 0; i < 8; ++i) {
    int c = t + i * 256;
    int kv = c >> 5, ds = (c & 31) * 4;
    float4 v = *(const float4*)(V + ((size_t)(b * LL + t0 + kv) * DD + ds));
    unsigned* dst = (unsigned*)(&lds[kv * 130 + ds]);
    dst[0] = cvtpk(v.x, v.y);
    dst[1] = cvtpk(v.z, v.w);
  }
  __syncthreads();
  int d = t >> 1, hf = t & 1;
  unsigned dw[16];
  #pragma unroll
  for (int i = 0; i < 16; ++i) {
    int kv = hf * 32 + i * 2;
    unsigned lo16 = (unsigned short)lds[kv * 130 + d];
    unsigned hi16 = (unsigned short)lds[(kv + 1) * 130 + d];
    dw[i] = lo16 | (hi16 << 16);
  }
  short* orow = Vt + (size_t)(b * DD + d) * LL + t0 + hf * 32;
  #pragma unroll
  for (int i = 0; i < 4; ++i)
    ((uint4*)orow)[i] = make_uint4(dw[4 * i], dw[4 * i + 1], dw[4 * i + 2], dw[4 * i + 3]);
}

// ---------------- main flash attention ----------------
// grid 256 (b, qblock of 128), 512 threads = 8 waves:
//   wave w: q-subtile qg = w&3 (32 rows), kv-half kvh = w>>2 (32 of each 64-kv tile)
// LDS: K dbuf 2x16KB @0, V dbuf 2x16KB @32768; merge region reuses it after loop.
__global__ __launch_bounds__(512, 2) void attn_main(
    const short* __restrict__ Qb, const short* __restrict__ Kb,
    const short* __restrict__ Vt, float* __restrict__ Out) {
  __shared__ __align__(16) char smem[67584];
  const int tid = threadIdx.x;
  const int w = tid >> 6, l = tid & 63, lo = l & 31, hi = l >> 5;
  const int qg = w & 3, kvh = w >> 2;

  // bijective XCD swizzle: each batch's 16 blocks -> one XCD
  int lg = (blockIdx.x & 7) * 32 + (blockIdx.x >> 3);
  int b = lg >> 4;
  int q0 = (lg & 15) * 128 + qg * 32;

  // Q fragments: lane l holds Q[q0+lo][dc*16 + hi*8 .. +8]
  short8 qf[8];
  const short* qp = Qb + (size_t)(b * LL + q0 + lo) * DD;
  #pragma unroll
  for (int dc = 0; dc < 8; ++dc)
    qf[dc] = *(const short8*)(qp + dc * 16 + hi * 8);

  const char* kgb = (const char*)(Kb + (size_t)b * (LL * DD));  // rows 256B
  const char* vgb = (const char*)(Vt + (size_t)b * (LL * DD));  // rows 4096B (d-major)

  // Stage one 64-kv tile: K tile [64][128]bf16 (rows 256B, swizzle key row&15),
  // V tile [128][64]bf16 (rows 128B, swizzle key row&7). Linear LDS dest,
  // inverse-swizzled global source (rule #21). 4 gll16 per wave.
#define STAGE(bi_, kv0_) do { \
    char* kbuf = smem + (bi_) * 16384; \
    char* vbuf = smem + 32768 + (bi_) * 16384; \
    _Pragma("unroll") \
    for (int i = 0; i < 2; ++i) { \
      int c = w * 2 + i; \
      int kr = c * 4 + (l >> 4); \
      int kc = ((l & 15) << 4) ^ ((kr & 15) << 4); \
      gll16(kgb + (size_t)((kv0_) + kr) * 256 + kc, kbuf + c * 1024); \
      int vr = c * 8 + (l >> 3); \
      int vc = ((l & 7) << 4) ^ ((vr & 7) << 4); \
      gll16(vgb + (size_t)vr * 4096 + (size_t)(kv0_) * 2 + vc, vbuf + c * 1024); \
    } \
  } while (0)

  STAGE(0, 0);
  __syncthreads();

  f32x16 oacc[4];
  #pragma unroll
  for (int dt = 0; dt < 4; ++dt)
    #pragma unroll
    for (int r = 0; r < 16; ++r) oacc[dt][r] = 0.f;
  float m = -INFINITY, lsum = 0.f;

  const int swzk = (lo & 15) << 4;   // K read key (row = kvh*32+lo, &15 == lo&15)
  const int swzv = (lo & 7) << 4;    // V read key (row = dt*32+lo, &7 == lo&7)

  #pragma unroll 1
  for (int tt = 0; tt < 32; ++tt) {
    int cur = tt & 1;
    if (tt < 31) STAGE(cur ^ 1, (tt + 1) * 64);
    const char* kb = smem + cur * 16384;
    const char* vb = smem + 32768 + cur * 16384;

    // --- QK^T (swapped): lane holds S[q=lo][kv=crow(r,hi)] of this wave's half
    f32x16 acc;
    #pragma unroll
    for (int r = 0; r < 16; ++r) acc[r] = 0.f;
    const char* krow = kb + (kvh * 32 + lo) * 256;
    #pragma unroll
    for (int dc = 0; dc < 8; ++dc) {
      short8 kf = *(const short8*)(krow + ((dc * 32 + hi * 16) ^ swzk));
      acc = __builtin_amdgcn_mfma_f32_32x32x16_bf16(kf, qf[dc], acc, 0, 0, 0);
    }
    // --- wave-group online max with defer threshold (T13)
    float tmax = acc[0];
    #pragma unroll
    for (int r = 1; r < 16; ++r) tmax = fmaxf(tmax, acc[r]);
    #pragma unroll
    for (int off = 1; off < 64; off <<= 1) tmax = fmaxf(tmax, __shfl_xor(tmax, off));
    if (tmax > m + 8.0f) {
      float al = wexp2((m - tmax) * LOG2E);
      m = tmax;
      lsum *= al;
      #pragma unroll
      for (int dt = 0; dt < 4; ++dt)
        #pragma unroll
        for (int r = 0; r < 16; ++r) oacc[dt][r] *= al;
    }
    float ps = 0.f;
    #pragma unroll
    for (int r = 0; r < 16; ++r) {
      float p = wexp2((acc[r] - m) * LOG2E);
      acc[r] = p; ps += p;
    }
    lsum += ps;
    // --- P -> bf16 A-frags (T12)
    short8 pa[2];
    #pragma unroll
    for (int ks = 0; ks < 2; ++ks) {
      unsigned a0 = cvtpk(acc[ks * 8 + 0], acc[ks * 8 + 1]);
      unsigned b0 = cvtpk(acc[ks * 8 + 4], acc[ks * 8 + 5]);
      unsigned c0 = cvtpk(acc[ks * 8 + 2], acc[ks * 8 + 3]);
      unsigned d0 = cvtpk(acc[ks * 8 + 6], acc[ks * 8 + 7]);
      asm volatile("v_permlane32_swap_b32 %0, %1" : "+v"(a0), "+v"(b0));
      asm volatile("v_permlane32_swap_b32 %0, %1" : "+v"(c0), "+v"(d0));
      union { unsigned u[4]; short8 s; } pu;
      pu.u[0] = a0; pu.u[1] = c0; pu.u[2] = b0; pu.u[3] = d0;
      pa[ks] = pu.s;
    }
    // --- PV over this wave's kv half
    #pragma unroll
    for (int dt = 0; dt < 4; ++dt) {
      const char* vrow = vb + (dt * 32 + lo) * 128;
      #pragma unroll
      for (int ks = 0; ks < 2; ++ks) {
        short8 vf = *(const short8*)(vrow + ((kvh * 64 + ks * 32 + hi * 16) ^ swzv));
        oacc[dt] = __builtin_amdgcn_mfma_f32_32x32x16_bf16(pa[ks], vf, oacc[dt], 0, 0, 0);
      }
    }
    __syncthreads();   // drains vmcnt(0): next tile staged, this tile's reads done
  }
#undef STAGE

  // ---- pair merge: wave (qg, kvh=1) publishes raw partials; (qg, kvh=0) merges.
  float* lsb = (float*)(smem + 65536);         // [4][64]
  float* mb  = (float*)(smem + 66560);         // [4]
  float* rdb = (float*)(smem + 66576);         // [4][32]
  if (kvh == 1) {
    #pragma unroll
    for (int dt = 0; dt < 4; ++dt)
      #pragma unroll
      for (int i = 0; i < 4; ++i)
        *(float4*)(smem + qg * 16384 + l * 256 + ((dt * 64 + i * 16) ^ ((l & 15) << 4))) =
            make_float4(oacc[dt][4 * i], oacc[dt][4 * i + 1],
                        oacc[dt][4 * i + 2], oacc[dt][4 * i + 3]);
    lsb[qg * 64 + l] = lsum;
    if (l == 0) mb[qg] = m;
  }
  __syncthreads();
  if (kvh == 0) {
    float mp = mb[qg];
    float M = fmaxf(m, mp);
    float aa = wexp2((m - M) * LOG2E), ab = wexp2((mp - M) * LOG2E);
    float ls = lsum * aa + lsb[qg * 64 + l] * ab;
    float lt = ls + __shfl_xor(ls, 32);
    float rd = 1.0f / lt;
    if (l < 32) rdb[qg * 32 + l] = rd;
    #pragma unroll
    for (int dt = 0; dt < 4; ++dt)
      #pragma unroll
      for (int i = 0; i < 4; ++i) {
        float4 p = *(const float4*)(smem + qg * 16384 + l * 256 +
                                    ((dt * 64 + i * 16) ^ ((l & 15) << 4)));
        oacc[dt][4 * i + 0] = oacc[dt][4 * i + 0] * aa + p.x * ab;
        oacc[dt][4 * i + 1] = oacc[dt][4 * i + 1] * aa + p.y * ab;
        oacc[dt][4 * i + 2] = oacc[dt][4 * i + 2] * aa + p.z * ab;
        oacc[dt][4 * i + 3] = oacc[dt][4 * i + 3] * aa + p.w * ab;
      }
    #pragma unroll
    for (int r = 0; r < 16; ++r) {
      int cr = (r & 3) + 8 * (r >> 2) + 4 * hi;
      float rr = rdb[qg * 32 + cr];
      float* op = Out + (size_t)(b * LL + q0 + cr) * DD + lo;
      #pragma unroll
      for (int dt = 0; dt < 4; ++dt)
        op[dt * 32] = oacc[dt][r] * rr;
    }
  }
}

extern "C" void kernel_launch(void* const* d_in, const int* in_sizes, int n_in,
                              void* d_out, int out_size, void* d_ws, size_t ws_size,
                              hipStream_t stream) {
  const float* Q = (const float*)d_in[0];
  const float* K = (const float*)d_in[1];
  const float* V = (const float*)d_in[2];
  const float* scale = (const float*)d_in[3];
  const int* mask = (const int*)d_in[4];
  float* out = (float*)d_out;

  const size_t tensor_elems = (size_t)NB * LL * DD;
  const size_t need = 3 * tensor_elems * sizeof(short);
  if (ws_size < need) return;

  short* Qb = (short*)d_ws;
  short* Kb = Qb + tensor_elems;
  short* Vtp = Kb + tensor_elems;

  hipLaunchKernelGGL(prep_qk, dim3(4096), dim3(256), 0, stream, Q, K, scale, mask, Qb, Kb);
  hipLaunchKernelGGL(prep_vt, dim3(512), dim3(256), 0, stream, V, Vtp);
  hipLaunchKernelGGL(attn_main, dim3(256), dim3(512), 0, stream, Qb, Kb, Vtp, out);
}